// Round 8
// baseline (25.804 us; speedup 1.0000x reference)
//
#include <hip/hip_runtime.h>
#include <math.h>

#define G 128
#define NCELLS (G*G)            // 16384
#define RAD 20
#define NS 41
#define NTAPS (NS*NS)           // 1681
#define NB_FULL 1850.0f         // 1 + (2R+3)^2 entries in the mean
#define NTAIL 168.0f            // (2R+3)^2 - (2R+1)^2
#define NRULES 4

#define CELLS_PB 32             // cells per block (quarter grid-row)
#define COLS 72                 // staged cols = 32 + 2*RAD
#define PLANE (NS*COLS)         // 2952 floats per channel plane
#define SROWPAD 44              // stencil row stride (41 + 3 zero pad)
#define BWSZ (NRULES*NS*SROWPAD) // 7216 floats block-private stencil scratch
#define NGRP 32                 // tap groups
#define NBLOCKS 512

__device__ __forceinline__ float kw(float d, float irk,
                                    float rk0, float rk1, float rk2,
                                    float b0, float b1, float b2,
                                    float iw0, float iw1, float iw2) {
    float em = 1.f / (1.f + __expf((d - 1.f) * 10.f));
    float dd = d * irk;
    float u0 = (dd - rk0) * iw0;
    float u1 = (dd - rk1) * iw1;
    float u2 = (dd - rk2) * iw2;
    return em * (b0 * __expf(-0.5f * u0 * u0)
               + b1 * __expf(-0.5f * u1 * u1)
               + b2 * __expf(-0.5f * u2 * u2));
}

// taps 4q..4q+3 (stencil chunk rq) vs window chunks wq,wq1 -> accumulator A.
// Ascending-tap FMA order per accumulator (matches prior rounds).
#define CROW(rq, wq, wq1, A)                                                      \
    A.x = fmaf(rq.x, wq.x,  A.x); A.y = fmaf(rq.x, wq.y,  A.y);                   \
    A.z = fmaf(rq.x, wq.z,  A.z); A.w = fmaf(rq.x, wq.w,  A.w);                   \
    A.x = fmaf(rq.y, wq.y,  A.x); A.y = fmaf(rq.y, wq.z,  A.y);                   \
    A.z = fmaf(rq.y, wq.w,  A.z); A.w = fmaf(rq.y, wq1.x, A.w);                   \
    A.x = fmaf(rq.z, wq.z,  A.x); A.y = fmaf(rq.z, wq.w,  A.y);                   \
    A.z = fmaf(rq.z, wq1.x, A.z); A.w = fmaf(rq.z, wq1.y, A.w);                   \
    A.x = fmaf(rq.w, wq.w,  A.x); A.y = fmaf(rq.w, wq1.x, A.y);                   \
    A.z = fmaf(rq.w, wq1.y, A.z); A.w = fmaf(rq.w, wq1.z, A.w);

// 512 blocks = 128 rows x 4 quarter-rows. 256 threads = 32 tap-groups x 8 col-lanes.
// Whole problem (conv for all 4 rules + growth + clip + pos) in ONE kernel.
__global__ __launch_bounds__(256)
void lenia_fused(const float* __restrict__ pos,
                 const float* __restrict__ x,
                 const int* __restrict__ c0v,
                 const int* __restrict__ c1v,
                 const float* __restrict__ rr,
                 const float* __restrict__ rkv,
                 const float* __restrict__ bv,
                 const float* __restrict__ wv,
                 const float* __restrict__ hv,
                 const float* __restrict__ mv,
                 const float* __restrict__ sv,
                 float* __restrict__ ws,
                 float* __restrict__ out) {
    __shared__ __align__(16) float xs[3*PLANE];   // 3 channel planes; aliased as partials later
    __shared__ float stail[NRULES];

    const int bid = blockIdx.x;
    const int t   = threadIdx.x;
    const int i   = bid >> 2;                     // grid row
    const int c0  = (bid & 3) * CELLS_PB;         // first owned column

    // ---- pos pass-through (independent of everything) ----
    {
        int base = bid * 64;                      // 512*64 = 32768
        if (t < 64) out[base + t] = pos[base + t];
    }

    // ---- stage 3 channel planes (rows i-20..i+20, cols c0-20..c0+51) ----
    for (int idx = t; idx < NS * COLS; idx += 256) {
        int rrow = idx / COLS;
        int cc   = idx - rrow * COLS;
        int grow = (i - RAD + rrow) & (G - 1);
        int gcol = (c0 - RAD + cc) & (G - 1);
        const float* xp = x + (grow * G + gcol) * 3;
        float v0 = xp[0], v1 = xp[1], v2 = xp[2];
        xs[0*PLANE + idx] = v0;
        xs[1*PLANE + idx] = v1;
        xs[2*PLANE + idx] = v2;
    }

    // ---- per-wave stencil: wave w computes rule w's full normalized stencil ----
    {
        const int w    = t >> 6;                  // rule handled by this wave
        const int lane = t & 63;
        const float irk = 1.f / rr[w];
        const float rk0 = rkv[w*3+0], rk1 = rkv[w*3+1], rk2 = rkv[w*3+2];
        const float b0  = bv[w*3+0],  b1  = bv[w*3+1],  b2  = bv[w*3+2];
        const float iw0 = 1.f / wv[w*3+0], iw1 = 1.f / wv[w*3+1], iw2 = 1.f / wv[w*3+2];
        const float invR = 1.f / (float)RAD;

        float vals[27];
        float lsum = 0.f;
        #pragma unroll
        for (int j = 0; j < 27; ++j) {
            int sidx = j * 64 + lane;
            float wk = 0.f;
            if (sidx < NTAPS) {
                int si = sidx / NS - RAD;
                int sj = sidx % NS - RAD;
                float d = sqrtf((float)(si*si + sj*sj)) * invR;
                wk = kw(d, irk, rk0, rk1, rk2, b0, b1, b2, iw0, iw1, iw2);
            }
            vals[j] = wk;
            lsum += wk;
        }
        #pragma unroll
        for (int mm = 32; mm > 0; mm >>= 1) lsum += __shfl_xor(lsum, mm, 64);
        const float wself = kw(0.f, irk, rk0, rk1, rk2, b0, b1, b2, iw0, iw1, iw2);
        const float dtail = sqrtf(8192.f) * invR;
        const float wtail = kw(dtail, irk, rk0, rk1, rk2, b0, b1, b2, iw0, iw1, iw2);
        const float S = lsum + wself + NTAIL * wtail;
        const float inv = 1.f / (S * NB_FULL);

        float* bwr = ws + (size_t)bid * BWSZ + w * NS * SROWPAD;
        #pragma unroll
        for (int j = 0; j < 27; ++j) {
            int sidx = j * 64 + lane;
            if (sidx < NTAPS) {
                float v = vals[j] * inv;
                if (sidx == RAD*NS + RAD) v += wself * inv;   // fold self slot into (0,0)
                bwr[(sidx / NS) * SROWPAD + (sidx % NS)] = v;
            }
        }
        for (int j = lane; j < NS * 3; j += 64)               // zero the 3 pad cols
            bwr[(j / 3) * SROWPAD + NS + (j % 3)] = 0.f;
        if (lane == 0) stail[w] = NTAIL * wtail * inv;
    }
    __syncthreads();   // xs staged; bw stores drained (waitcnt before barrier)

    // ---- conv: tap-group g covers stencil rows si0..si0+nsi-1, all 4 rules ----
    const int g   = t >> 3;                       // 0..31
    const int lc  = t & 7;                        // col-group: cells lc*4..lc*4+3
    const int nsi = (g < 9) ? 2 : 1;              // 9x2 + 23x1 = 41 rows
    const int si0 = (g < 9) ? 2*g : 18 + (g - 9);

    float4 acc[4];
    #pragma unroll
    for (int k = 0; k < 4; ++k) { acc[k].x = 0.f; acc[k].y = 0.f; acc[k].z = 0.f; acc[k].w = 0.f; }

    #pragma unroll
    for (int k = 0; k < 4; ++k) {
        const int ck = c0v[k];                    // wave-uniform
        const float* plane = xs + ck * PLANE;
        const float* bk = ws + (size_t)bid * BWSZ + k * NS * SROWPAD;
        #pragma unroll
        for (int ii = 0; ii < 2; ++ii) {
            if (ii < nsi) {
                const float4* wp = (const float4*)(plane + (si0 + ii) * COLS + lc * 4);
                const float4* rp = (const float4*)(bk + (si0 + ii) * SROWPAD);
                float4 w0 = wp[0], w1 = wp[1], w2 = wp[2], w3 = wp[3], w4 = wp[4], w5 = wp[5];
                float4 w6 = wp[6], w7 = wp[7], w8 = wp[8], w9 = wp[9], w10 = wp[10];
                float4 r0 = rp[0], r1 = rp[1], r2 = rp[2], r3 = rp[3], r4 = rp[4], r5 = rp[5];
                float4 r6 = rp[6], r7 = rp[7], r8 = rp[8], r9 = rp[9], r10 = rp[10];
                CROW(r0, w0, w1, acc[k])  CROW(r1, w1, w2, acc[k])
                CROW(r2, w2, w3, acc[k])  CROW(r3, w3, w4, acc[k])
                CROW(r4, w4, w5, acc[k])  CROW(r5, w5, w6, acc[k])
                CROW(r6, w6, w7, acc[k])  CROW(r7, w7, w8, acc[k])
                CROW(r8, w8, w9, acc[k])  CROW(r9, w9, w10, acc[k])
                acc[k].x = fmaf(r10.x, w10.x, acc[k].x);      // tap 40 (41..43 are zero)
                acc[k].y = fmaf(r10.x, w10.y, acc[k].y);
                acc[k].z = fmaf(r10.x, w10.z, acc[k].z);
                acc[k].w = fmaf(r10.x, w10.w, acc[k].w);
            }
        }
    }
    __syncthreads();                              // all xs reads done -> safe to alias

    // ---- partials into LDS alias: P[rule][group][cell] ----
    float* P = xs;
    #pragma unroll
    for (int k = 0; k < 4; ++k) {
        int base = ((k * NGRP + g) << 5) + lc * 4;
        P[base + 0] = acc[k].x;
        P[base + 1] = acc[k].y;
        P[base + 2] = acc[k].z;
        P[base + 3] = acc[k].w;
    }
    __syncthreads();

    // ---- growth + delta + clip for the block's 32 cells ----
    if (t < CELLS_PB) {
        int cell = i * G + c0 + t;
        float xv0 = x[cell*3 + 0], xv1 = x[cell*3 + 1], xv2 = x[cell*3 + 2];
        float d0 = 0.f, d1 = 0.f, d2 = 0.f;
        #pragma unroll
        for (int k = 0; k < 4; ++k) {
            float pot = stail[k] * x[c0v[k]];     // tail slots all index cell 0
            for (int g2 = 0; g2 < NGRP; ++g2)     // ascending row-slices (deterministic)
                pot += P[((k * NGRP + g2) << 5) + t];
            float u = pot - mv[k];
            float sk = sv[k];
            float field = __expf(-u*u / (2.f * sk * sk) - 0.001f) * 2.f - 1.f;
            float add = hv[k] * field;
            int c = c1v[k];
            if (c == 0) d0 += add; else if (c == 1) d1 += add; else d2 += add;
        }
        float* ox = out + 2 * NCELLS;
        ox[cell*3 + 0] = fminf(fmaxf(xv0 + d0 * 0.1f, 0.f), 1.f);
        ox[cell*3 + 1] = fminf(fmaxf(xv1 + d1 * 0.1f, 0.f), 1.f);
        ox[cell*3 + 2] = fminf(fmaxf(xv2 + d2 * 0.1f, 0.f), 1.f);
    }
}

extern "C" void kernel_launch(void* const* d_in, const int* in_sizes, int n_in,
                              void* d_out, int out_size, void* d_ws, size_t ws_size,
                              hipStream_t stream) {
    const float* pos = (const float*)d_in[0];
    const float* x   = (const float*)d_in[1];
    const int*   c0  = (const int*)  d_in[2];
    const int*   c1  = (const int*)  d_in[3];
    const float* r   = (const float*)d_in[4];
    const float* rk  = (const float*)d_in[5];
    const float* b   = (const float*)d_in[6];
    const float* w   = (const float*)d_in[7];
    const float* h   = (const float*)d_in[8];
    const float* m   = (const float*)d_in[9];
    const float* s   = (const float*)d_in[10];
    float* out = (float*)d_out;
    float* ws  = (float*)d_ws;

    lenia_fused<<<NBLOCKS, 256, 0, stream>>>(pos, x, c0, c1, r, rk, b, w, h, m, s, ws, out);
}